// Round 11
// baseline (165.072 us; speedup 1.0000x reference)
//
#include <hip/hip_runtime.h>

typedef __bf16 bf16x8 __attribute__((ext_vector_type(8)));
typedef float  f32x4  __attribute__((ext_vector_type(4)));
typedef unsigned short u16;
typedef unsigned int   u32;

#define MFMA16(a,b,c) __builtin_amdgcn_mfma_f32_16x16x32_bf16((a),(b),(c),0,0,0)

__device__ __forceinline__ u16 f2bf(float f){
    u32 u = __builtin_bit_cast(u32, f);
    u += 0x7FFFu + ((u >> 16) & 1u);   // RNE
    return (u16)(u >> 16);
}

__device__ __forceinline__ u32 cvt_pk_bf16(float lo, float hi){
    u32 r;
    asm("v_cvt_pk_bf16_f32 %0, %1, %2" : "=v"(r) : "v"(lo), "v"(hi));
    return r;
}

__device__ __forceinline__ float max3f(float a, float b, float c){
    return fmaxf(fmaxf(a, b), c);
}

typedef __attribute__((address_space(3))) u32 lds32_t;
typedef __attribute__((address_space(1))) u32 glb32_t;

__device__ __forceinline__ void gll16(const u16* g, u16* l){
    __builtin_amdgcn_global_load_lds((const glb32_t*)g, (lds32_t*)l, 16, 0, 0);
}

// ---------------- merged convert kernel: cvt_x + tcvt(w_qkv) + tcvt(w_out) ----------------
__device__ __forceinline__ void tcvt_body(const float* __restrict__ in, u16* __restrict__ out,
                                          int R, int C, int bx, int by){
    __shared__ float tile[32][33];
    int c0 = bx * 32, r0 = by * 32;
    int tx = threadIdx.x & 31, ty = threadIdx.x >> 5;   // ty 0..7
    #pragma unroll
    for (int i = 0; i < 32; i += 8)
        tile[ty + i][tx] = in[(size_t)(r0 + ty + i) * C + c0 + tx];
    __syncthreads();
    #pragma unroll
    for (int i = 0; i < 32; i += 8)
        out[(size_t)(c0 + ty + i) * R + r0 + tx] = f2bf(tile[tx][ty + i]);
}

__global__ __launch_bounds__(256) void cvt_all_kernel(const float* __restrict__ x,
                                                      const float* __restrict__ w_qkv,
                                                      const float* __restrict__ w_out,
                                                      u16* __restrict__ xbf,
                                                      u16* __restrict__ wqt,
                                                      u16* __restrict__ wot){
    const int bid = blockIdx.x;
    if (bid < 2048){
        // x fp32 -> bf16, 8 elems/thread
        int i = bid * 256 + threadIdx.x;
        const float4* p = (const float4*)x + (size_t)i * 2;
        float4 a = p[0], b = p[1];
        u16 r[8] = { f2bf(a.x), f2bf(a.y), f2bf(a.z), f2bf(a.w),
                     f2bf(b.x), f2bf(b.y), f2bf(b.z), f2bf(b.w) };
        *((uint4*)xbf + i) = *(const uint4*)r;
    } else if (bid < 2816){
        int b2 = bid - 2048;                      // 768 blocks: 48 x 16
        tcvt_body(w_qkv, wqt, 512, 1536, b2 % 48, b2 / 48);
    } else {
        int b3 = bid - 2816;                      // 256 blocks: 16 x 16
        tcvt_body(w_out, wot, 512, 512, b3 % 16, b3 / 16);
    }
}

// ---------------- shared GEMM mainloop ----------------
__device__ __forceinline__ void gemm_core(const u16* __restrict__ A, const u16* __restrict__ Bt,
                                          int brow, int bcol, u16* ldsA, u16* ldsB,
                                          f32x4 acc[4][4]){
    const int t = threadIdx.x;
    const int lane = t & 63, wave = t >> 6;
    const int l16 = lane & 15, lg = lane >> 4;
    const int wrow = (wave & 1) << 6, wcol = (wave >> 1) << 6;

    for (int ks = 0; ks < 8; ++ks){
        if (ks) __syncthreads();
        #pragma unroll
        for (int iss = 0; iss < 4; ++iss){
            int chunk = iss * 256 + t;
            int row = chunk >> 3, c = chunk & 7;
            int sw = (c ^ (row & 7)) << 3;
            gll16(A  + (size_t)(brow + row) * 512 + ks * 64 + sw,
                  ldsA + (size_t)(iss * 256 + wave * 64) * 8);
            gll16(Bt + (size_t)(bcol + row) * 512 + ks * 64 + sw,
                  ldsB + (size_t)(iss * 256 + wave * 64) * 8);
        }
        __syncthreads();
        #pragma unroll
        for (int kc = 0; kc < 2; ++kc){
            bf16x8 af[4], bfr[4];
            #pragma unroll
            for (int m = 0; m < 4; ++m){
                int r = wrow + 16 * m + l16;
                af[m] = *(const bf16x8*)(ldsA + r * 64 + (((kc * 4 + lg) ^ (l16 & 7)) << 3));
            }
            #pragma unroll
            for (int n = 0; n < 4; ++n){
                int r = wcol + 16 * n + l16;
                bfr[n] = *(const bf16x8*)(ldsB + r * 64 + (((kc * 4 + lg) ^ (l16 & 7)) << 3));
            }
            #pragma unroll
            for (int m = 0; m < 4; ++m)
                #pragma unroll
                for (int n = 0; n < 4; ++n)
                    acc[m][n] = MFMA16(af[m], bfr[n], acc[m][n]);
        }
    }
}

// ---------------- GEMM1: qkv; XCD-remapped 1D grid (768 = 8 xcd * 8 brow * 12 bcol) ----------------
__global__ __launch_bounds__(256) void gemm_qkv_kernel(const u16* __restrict__ A, const u16* __restrict__ Bt,
                                                       u16* __restrict__ qws, u16* __restrict__ kws,
                                                       u16* __restrict__ vtws,
                                                       const float* __restrict__ temp){
    __shared__ u16 ldsA[128 * 64];
    __shared__ u16 ldsB[128 * 64];
    const f32x4 vzero = {0.f, 0.f, 0.f, 0.f};
    f32x4 acc[4][4];
    #pragma unroll
    for (int m = 0; m < 4; ++m)
        #pragma unroll
        for (int n = 0; n < 4; ++n) acc[m][n] = vzero;

    // XCD-aware remap: each XCD owns 8 contiguous brow-blocks x all 12 bcol-blocks
    const int bid = blockIdx.x;                 // [0,768)
    const int xcd = bid & 7, idx = bid >> 3;    // idx in [0,96)
    int brow = (xcd * 8 + (idx & 7)) * 128;     // brow-block in [0,64)
    int bcol = (idx >> 3) * 128;                // bcol-block in [0,12)
    gemm_core(A, Bt, brow, bcol, ldsA, ldsB, acc);

    const int t = threadIdx.x, lane = t & 63, wave = t >> 6;
    const int l16 = lane & 15, lg = lane >> 4;
    const int wrow = (wave & 1) << 6, wcol = (wave >> 1) << 6;
    const int s = bcol >> 9;            // 0:q 1:k 2:v (uniform per block)

    if (s < 2){
        u16* dst = (s == 0) ? qws : kws;
        float qs = (s == 0) ? (__expf(temp[0]) * 1.44269504f) : 1.0f;
        #pragma unroll
        for (int n = 0; n < 4; ++n){
            int e = (bcol & 511) + wcol + 16 * n + l16;
            int h = e >> 6, d = e & 63;
            #pragma unroll
            for (int m = 0; m < 4; ++m)
                #pragma unroll
                for (int r = 0; r < 4; ++r){
                    int mg = brow + wrow + 16 * m + 4 * lg + r;
                    int b = mg >> 12, nn = mg & 4095;
                    dst[(((size_t)(b * 8 + h) * 4096 + nn) << 6) + d] = f2bf(acc[m][n][r] * qs);
                }
        }
    } else {
        #pragma unroll
        for (int n = 0; n < 4; ++n){
            int e = (bcol & 511) + wcol + 16 * n + l16;
            int h = e >> 6, d = e & 63;
            #pragma unroll
            for (int m = 0; m < 4; ++m)
                #pragma unroll
                for (int r = 0; r < 4; ++r){
                    int mg = brow + wrow + 16 * m + 4 * lg + r;
                    int b = mg >> 12, nn = mg & 4095;
                    vtws[((size_t)((b * 8 + h) * 64 + d) << 12) + nn] = f2bf(acc[m][n][r]);
                }
        }
    }
}

// ---------------- flash attention: R7 compute, gll16 staging (no wave DS-issue), XCD swizzle ----------------
__global__ __launch_bounds__(256) void attn_kernel(const u16* __restrict__ q, const u16* __restrict__ k,
                                                   const u16* __restrict__ vt, u16* __restrict__ aout){
    __shared__ u16 Kl[64 * 64];          // [kv][64] swizzled
    __shared__ u16 Vl[64 * 64];          // [d][kv] swizzled
    __shared__ u16 Pl[4][16 * 72];       // per-wave P tile [q][kv], padded rows
    const int bid0 = blockIdx.x;
    const int bid = (bid0 & 7) * 128 + (bid0 >> 3);   // XCD-grouped: 2 bh per XCD (bijection)
    const int qt = bid & 63, bh = bid >> 6;
    const int t = threadIdx.x, lane = t & 63, wave = t >> 6;
    const int l16 = lane & 15, lg = lane >> 4;

    // gll16 staging: pre-swizzled global source, linear LDS dest (TA-path LDS writes)
    auto stage = [&](int kb){
        #pragma unroll
        for (int iss = 0; iss < 2; ++iss){
            int chunk = iss * 256 + t;
            int row = chunk >> 3, c = chunk & 7;
            int sw = (c ^ (row & 7)) << 3;
            gll16(k  + (((size_t)bh * 4096 + kb + row) << 6) + sw,
                  Kl + (iss * 256 + t) * 8 - iss * 256 * 8 + iss * 256 * 8);
            gll16(vt + ((size_t)(bh * 64 + row) << 12) + kb + sw,
                  Vl + (iss * 256 + t) * 8 - iss * 256 * 8 + iss * 256 * 8);
        }
    };
    (void)stage;
    // NOTE: the expression above must match R4's verified wave-uniform-base form; restated cleanly:
    auto stage2 = [&](int kb){
        #pragma unroll
        for (int iss = 0; iss < 2; ++iss){
            int chunk = iss * 256 + t;
            int row = chunk >> 3, c = chunk & 7;
            int sw = (c ^ (row & 7)) << 3;
            gll16(k  + (((size_t)bh * 4096 + kb + row) << 6) + sw,
                  Kl + (iss * 256 + wave * 64) * 8);
            gll16(vt + ((size_t)(bh * 64 + row) << 12) + kb + sw,
                  Vl + (iss * 256 + wave * 64) * 8);
        }
    };

    // lane-local q row (q already pre-scaled by exp(temp)*log2e)
    const int qrow = qt * 64 + wave * 16 + l16;
    const u16* qb = q + (((size_t)bh * 4096 + qrow) << 6);
    bf16x8 qa[2];
    qa[0] = *(const bf16x8*)(qb + (lg << 3));
    qa[1] = *(const bf16x8*)(qb + 32 + (lg << 3));

    const uint4 ow = {0x3F803F80u, 0x3F803F80u, 0x3F803F80u, 0x3F803F80u};
    const bf16x8 ones = __builtin_bit_cast(bf16x8, ow);

    const f32x4 vzero = {0.f, 0.f, 0.f, 0.f};
    f32x4 o[4];                                  // o[dn][r] = O[q=l16][d=16dn+4lg+r]
    f32x4 o4 = vzero;                            // running denominator (all rows equal)
    #pragma unroll
    for (int i = 0; i < 4; ++i) o[i] = vzero;
    float mv = -INFINITY;                        // running max for row q=l16 (lane-local)

    for (int kb = 0; kb < 4096; kb += 64){
        __syncthreads();
        stage2(kb);
        __syncthreads();

        // S^T = K Q^T : lane holds S[q=l16][kv=16fc+4lg+r]  (log2 domain)
        f32x4 s[4];
        __builtin_amdgcn_s_setprio(1);
        #pragma unroll
        for (int fc = 0; fc < 4; ++fc){
            s[fc] = vzero;
            #pragma unroll
            for (int dc = 0; dc < 2; ++dc){
                bf16x8 kf = *(const bf16x8*)(Kl + (16 * fc + l16) * 64 +
                                             (((dc * 4 + lg) ^ (l16 & 7)) << 3));
                s[fc] = MFMA16(kf, qa[dc], s[fc]);
            }
        }
        __builtin_amdgcn_s_setprio(0);
        // diagonal mask: only in the tile containing this block's q range
        if (kb == qt * 64){
            int dd = wave * 16 + l16;            // kv offset of the diagonal for this lane
            #pragma unroll
            for (int fc = 0; fc < 4; ++fc)
                #pragma unroll
                for (int r = 0; r < 4; ++r)
                    if (dd == fc * 16 + 4 * lg + r) s[fc][r] = -1e30f;
        }
        // row max: max3 tree (8 ops) + 2 cross-lane steps
        float g0 = max3f(s[0][0], s[0][1], s[0][2]);
        float g1 = max3f(s[0][3], s[1][0], s[1][1]);
        float g2 = max3f(s[1][2], s[1][3], s[2][0]);
        float g3 = max3f(s[2][1], s[2][2], s[2][3]);
        float g4 = max3f(s[3][0], s[3][1], s[3][2]);
        float pm = fmaxf(max3f(max3f(g0, g1, g2), g3, g4), s[3][3]);
        pm = fmaxf(pm, __shfl_xor(pm, 16));
        pm = fmaxf(pm, __shfl_xor(pm, 32));
        // defer-max: rescale only when the running max grew materially
        if (__any(pm > mv + 8.0f)){
            float mn = fmaxf(mv, pm);
            float al = __builtin_amdgcn_exp2f(mv - mn);
            mv = mn;
            o4 *= al;
            #pragma unroll
            for (int dn = 0; dn < 4; ++dn)
                #pragma unroll
                for (int r = 0; r < 4; ++r) o[dn][r] *= al;
        }
        // P = exp2(S - m) -> bf16 pack via cvt_pk; denominator comes from ones-MFMA below
        #pragma unroll
        for (int fc = 0; fc < 4; ++fc){
            float p0 = __builtin_amdgcn_exp2f(s[fc][0] - mv);
            float p1 = __builtin_amdgcn_exp2f(s[fc][1] - mv);
            float p2 = __builtin_amdgcn_exp2f(s[fc][2] - mv);
            float p3 = __builtin_amdgcn_exp2f(s[fc][3] - mv);
            uint2 w;
            w.x = cvt_pk_bf16(p0, p1);
            w.y = cvt_pk_bf16(p2, p3);
            *(uint2*)&Pl[wave][l16 * 72 + 16 * fc + 4 * lg] = w;
        }
        // O^T += V^T P^T ; denominator row via ones-operand MFMA
        __builtin_amdgcn_s_setprio(1);
        #pragma unroll
        for (int kc = 0; kc < 2; ++kc){
            bf16x8 pa = *(const bf16x8*)(&Pl[wave][l16 * 72 + kc * 32 + lg * 8]);
            o4 = MFMA16(ones, pa, o4);
            #pragma unroll
            for (int dn = 0; dn < 4; ++dn){
                bf16x8 vf = *(const bf16x8*)(Vl + (16 * dn + l16) * 64 +
                                             (((kc * 4 + lg) ^ (l16 & 7)) << 3));
                o[dn] = MFMA16(vf, pa, o[dn]);
            }
        }
        __builtin_amdgcn_s_setprio(0);
    }
    // epilogue: lane owns row q=l16; d = 16*dn + 4*lg + r (r contiguous -> b64 stores)
    const int b = bh >> 3, h = bh & 7;
    const float inv = __builtin_amdgcn_rcpf(o4[0]);
    const int n = qt * 64 + wave * 16 + l16;
    size_t base = ((size_t)b * 4096 + n) * 512 + h * 64;
    #pragma unroll
    for (int dn = 0; dn < 4; ++dn){
        u16 e0 = f2bf(o[dn][0] * inv), e1 = f2bf(o[dn][1] * inv);
        u16 e2 = f2bf(o[dn][2] * inv), e3 = f2bf(o[dn][3] * inv);
        uint2 w;
        w.x = (u32)e0 | ((u32)e1 << 16);
        w.y = (u32)e2 | ((u32)e3 << 16);
        *(uint2*)&aout[base + dn * 16 + lg * 4] = w;
    }
}

// ---------------- GEMM2: out = aout @ w_out^T + bias; XCD-remapped (256 = 8*8*4) ----------------
__global__ __launch_bounds__(256) void gemm_out_kernel(const u16* __restrict__ A, const u16* __restrict__ Bt,
                                                       const float* __restrict__ bias,
                                                       float* __restrict__ out){
    __shared__ u16 ldsA[128 * 64];
    __shared__ u16 ldsB[128 * 64];
    const f32x4 vzero = {0.f, 0.f, 0.f, 0.f};
    f32x4 acc[4][4];
    #pragma unroll
    for (int m = 0; m < 4; ++m)
        #pragma unroll
        for (int n = 0; n < 4; ++n) acc[m][n] = vzero;

    const int bid = blockIdx.x;                 // [0,256)
    const int xcd = bid & 7, idx = bid >> 3;    // idx in [0,32)
    int brow = (xcd * 8 + (idx & 7)) * 128;     // brow-block in [0,64)
    int bcol = (idx >> 3) * 128;                // bcol-block in [0,4)
    gemm_core(A, Bt, brow, bcol, ldsA, ldsB, acc);

    const int t = threadIdx.x, lane = t & 63, wave = t >> 6;
    const int l16 = lane & 15, lg = lane >> 4;
    const int wrow = (wave & 1) << 6, wcol = (wave >> 1) << 6;
    #pragma unroll
    for (int n = 0; n < 4; ++n){
        int e = bcol + wcol + 16 * n + l16;
        float bv = bias[e];
        #pragma unroll
        for (int m = 0; m < 4; ++m)
            #pragma unroll
            for (int r = 0; r < 4; ++r){
                int mg = brow + wrow + 16 * m + 4 * lg + r;
                out[(size_t)mg * 512 + e] = acc[m][n][r] + bv;
            }
    }
}

extern "C" void kernel_launch(void* const* d_in, const int* in_sizes, int n_in,
                              void* d_out, int out_size, void* d_ws, size_t ws_size,
                              hipStream_t stream){
    (void)in_sizes; (void)n_in; (void)out_size; (void)ws_size;
    const float* x     = (const float*)d_in[0];
    const float* w_qkv = (const float*)d_in[1];
    const float* w_out = (const float*)d_in[2];
    const float* b_out = (const float*)d_in[3];
    const float* temp  = (const float*)d_in[4];
    float* out = (float*)d_out;

    u16* ws   = (u16*)d_ws;
    u16* xbf  = ws;                              // 8192*512
    u16* wqt  = xbf + 8192 * 512;                // 1536*512
    u16* wot  = wqt + 1536 * 512;                // 512*512
    u16* qws  = wot + 512 * 512;                 // 16*4096*64
    u16* kws  = qws + 16 * 4096 * 64;
    u16* vtws = kws + 16 * 4096 * 64;
    u16* aout = xbf;                             // alias: xbf dead after GEMM1

    cvt_all_kernel<<<3072, 256, 0, stream>>>(x, w_qkv, w_out, xbf, wqt, wot);
    gemm_qkv_kernel<<<768, 256, 0, stream>>>(xbf, wqt, qws, kws, vtws, temp);
    attn_kernel<<<1024, 256, 0, stream>>>(qws, kws, vtws, aout);
    gemm_out_kernel<<<256, 256, 0, stream>>>(aout, wot, b_out, out);
}

// Round 12
// 162.007 us; speedup vs baseline: 1.0189x; 1.0189x over previous
//
#include <hip/hip_runtime.h>

typedef __bf16 bf16x8 __attribute__((ext_vector_type(8)));
typedef float  f32x4  __attribute__((ext_vector_type(4)));
typedef unsigned short u16;
typedef unsigned int   u32;

#define MFMA16(a,b,c) __builtin_amdgcn_mfma_f32_16x16x32_bf16((a),(b),(c),0,0,0)

__device__ __forceinline__ u16 f2bf(float f){
    u32 u = __builtin_bit_cast(u32, f);
    u += 0x7FFFu + ((u >> 16) & 1u);   // RNE
    return (u16)(u >> 16);
}

__device__ __forceinline__ u32 cvt_pk_bf16(float lo, float hi){
    u32 r;
    asm("v_cvt_pk_bf16_f32 %0, %1, %2" : "=v"(r) : "v"(lo), "v"(hi));
    return r;
}

__device__ __forceinline__ float max3f(float a, float b, float c){
    return fmaxf(fmaxf(a, b), c);
}

typedef __attribute__((address_space(3))) u32 lds32_t;
typedef __attribute__((address_space(1))) u32 glb32_t;

__device__ __forceinline__ void gll16(const u16* g, u16* l){
    __builtin_amdgcn_global_load_lds((const glb32_t*)g, (lds32_t*)l, 16, 0, 0);
}

// ---------------- merged convert kernel: cvt_x + tcvt(w_qkv) + tcvt(w_out) ----------------
__device__ __forceinline__ void tcvt_body(const float* __restrict__ in, u16* __restrict__ out,
                                          int R, int C, int bx, int by){
    __shared__ float tile[32][33];
    int c0 = bx * 32, r0 = by * 32;
    int tx = threadIdx.x & 31, ty = threadIdx.x >> 5;   // ty 0..7
    #pragma unroll
    for (int i = 0; i < 32; i += 8)
        tile[ty + i][tx] = in[(size_t)(r0 + ty + i) * C + c0 + tx];
    __syncthreads();
    #pragma unroll
    for (int i = 0; i < 32; i += 8)
        out[(size_t)(c0 + ty + i) * R + r0 + tx] = f2bf(tile[tx][ty + i]);
}

__global__ __launch_bounds__(256) void cvt_all_kernel(const float* __restrict__ x,
                                                      const float* __restrict__ w_qkv,
                                                      const float* __restrict__ w_out,
                                                      u16* __restrict__ xbf,
                                                      u16* __restrict__ wqt,
                                                      u16* __restrict__ wot){
    const int bid = blockIdx.x;
    if (bid < 2048){
        // x fp32 -> bf16, 8 elems/thread
        int i = bid * 256 + threadIdx.x;
        const float4* p = (const float4*)x + (size_t)i * 2;
        float4 a = p[0], b = p[1];
        u16 r[8] = { f2bf(a.x), f2bf(a.y), f2bf(a.z), f2bf(a.w),
                     f2bf(b.x), f2bf(b.y), f2bf(b.z), f2bf(b.w) };
        *((uint4*)xbf + i) = *(const uint4*)r;
    } else if (bid < 2816){
        int b2 = bid - 2048;                      // 768 blocks: 48 x 16
        tcvt_body(w_qkv, wqt, 512, 1536, b2 % 48, b2 / 48);
    } else {
        int b3 = bid - 2816;                      // 256 blocks: 16 x 16
        tcvt_body(w_out, wot, 512, 512, b3 % 16, b3 / 16);
    }
}

// ---------------- shared GEMM mainloop ----------------
__device__ __forceinline__ void gemm_core(const u16* __restrict__ A, const u16* __restrict__ Bt,
                                          int brow, int bcol, u16* ldsA, u16* ldsB,
                                          f32x4 acc[4][4]){
    const int t = threadIdx.x;
    const int lane = t & 63, wave = t >> 6;
    const int l16 = lane & 15, lg = lane >> 4;
    const int wrow = (wave & 1) << 6, wcol = (wave >> 1) << 6;

    for (int ks = 0; ks < 8; ++ks){
        if (ks) __syncthreads();
        #pragma unroll
        for (int iss = 0; iss < 4; ++iss){
            int chunk = iss * 256 + t;
            int row = chunk >> 3, c = chunk & 7;
            int sw = (c ^ (row & 7)) << 3;
            gll16(A  + (size_t)(brow + row) * 512 + ks * 64 + sw,
                  ldsA + (size_t)(iss * 256 + wave * 64) * 8);
            gll16(Bt + (size_t)(bcol + row) * 512 + ks * 64 + sw,
                  ldsB + (size_t)(iss * 256 + wave * 64) * 8);
        }
        __syncthreads();
        #pragma unroll
        for (int kc = 0; kc < 2; ++kc){
            bf16x8 af[4], bfr[4];
            #pragma unroll
            for (int m = 0; m < 4; ++m){
                int r = wrow + 16 * m + l16;
                af[m] = *(const bf16x8*)(ldsA + r * 64 + (((kc * 4 + lg) ^ (l16 & 7)) << 3));
            }
            #pragma unroll
            for (int n = 0; n < 4; ++n){
                int r = wcol + 16 * n + l16;
                bfr[n] = *(const bf16x8*)(ldsB + r * 64 + (((kc * 4 + lg) ^ (l16 & 7)) << 3));
            }
            #pragma unroll
            for (int m = 0; m < 4; ++m)
                #pragma unroll
                for (int n = 0; n < 4; ++n)
                    acc[m][n] = MFMA16(af[m], bfr[n], acc[m][n]);
        }
    }
}

// ---------------- GEMM1: qkv; XCD-remapped 1D grid (768 = 8 xcd * 8 brow * 12 bcol) ----------------
__global__ __launch_bounds__(256) void gemm_qkv_kernel(const u16* __restrict__ A, const u16* __restrict__ Bt,
                                                       u16* __restrict__ qws, u16* __restrict__ kws,
                                                       u16* __restrict__ vtws,
                                                       const float* __restrict__ temp){
    __shared__ u16 ldsA[128 * 64];
    __shared__ u16 ldsB[128 * 64];
    const f32x4 vzero = {0.f, 0.f, 0.f, 0.f};
    f32x4 acc[4][4];
    #pragma unroll
    for (int m = 0; m < 4; ++m)
        #pragma unroll
        for (int n = 0; n < 4; ++n) acc[m][n] = vzero;

    // XCD-aware remap: each XCD owns 8 contiguous brow-blocks x all 12 bcol-blocks
    const int bid = blockIdx.x;                 // [0,768)
    const int xcd = bid & 7, idx = bid >> 3;    // idx in [0,96)
    int brow = (xcd * 8 + (idx & 7)) * 128;     // brow-block in [0,64)
    int bcol = (idx >> 3) * 128;                // bcol-block in [0,12)
    gemm_core(A, Bt, brow, bcol, ldsA, ldsB, acc);

    const int t = threadIdx.x, lane = t & 63, wave = t >> 6;
    const int l16 = lane & 15, lg = lane >> 4;
    const int wrow = (wave & 1) << 6, wcol = (wave >> 1) << 6;
    const int s = bcol >> 9;            // 0:q 1:k 2:v (uniform per block)

    if (s < 2){
        u16* dst = (s == 0) ? qws : kws;
        float qs = (s == 0) ? (__expf(temp[0]) * 1.44269504f) : 1.0f;
        #pragma unroll
        for (int n = 0; n < 4; ++n){
            int e = (bcol & 511) + wcol + 16 * n + l16;
            int h = e >> 6, d = e & 63;
            #pragma unroll
            for (int m = 0; m < 4; ++m)
                #pragma unroll
                for (int r = 0; r < 4; ++r){
                    int mg = brow + wrow + 16 * m + 4 * lg + r;
                    int b = mg >> 12, nn = mg & 4095;
                    dst[(((size_t)(b * 8 + h) * 4096 + nn) << 6) + d] = f2bf(acc[m][n][r] * qs);
                }
        }
    } else {
        // v path: nn has r as its stride-1 fastest index -> 4 bf16 = one dwordx2 store
        #pragma unroll
        for (int n = 0; n < 4; ++n){
            int e = (bcol & 511) + wcol + 16 * n + l16;
            int h = e >> 6, d = e & 63;
            #pragma unroll
            for (int m = 0; m < 4; ++m){
                int mg0 = brow + wrow + 16 * m + 4 * lg;      // 4-aligned; r=0..3 same b
                int b = mg0 >> 12, nn0 = mg0 & 4095;
                u16 e0 = f2bf(acc[m][n][0]), e1 = f2bf(acc[m][n][1]);
                u16 e2 = f2bf(acc[m][n][2]), e3 = f2bf(acc[m][n][3]);
                uint2 w;
                w.x = (u32)e0 | ((u32)e1 << 16);
                w.y = (u32)e2 | ((u32)e3 << 16);
                *(uint2*)&vtws[((size_t)((b * 8 + h) * 64 + d) << 12) + nn0] = w;
            }
        }
    }
}

// ---------------- flash attention: R9 verbatim (verified session best) ----------------
__global__ __launch_bounds__(256) void attn_kernel(const u16* __restrict__ q, const u16* __restrict__ k,
                                                   const u16* __restrict__ vt, u16* __restrict__ aout){
    __shared__ u16 Kl[64 * 64];          // [kv][64] swizzled
    __shared__ u16 Vl[64 * 64];          // [d][kv] swizzled
    __shared__ u16 Pl[4][16 * 72];       // per-wave P tile [q][kv], padded rows
    const int bid0 = blockIdx.x;
    const int bid = (bid0 & 7) * 128 + (bid0 >> 3);   // XCD-grouped: 2 bh per XCD (bijection)
    const int qt = bid & 63, bh = bid >> 6;
    const int t = threadIdx.x, lane = t & 63, wave = t >> 6;
    const int l16 = lane & 15, lg = lane >> 4;

    // T14 staging: per-thread chunk addresses (pre-swizzled global source, linear LDS dest)
    const int row0 = t >> 3,        sw0 = (((t & 7)        ^ (row0 & 7)) << 3);
    const int row1 = (256 + t) >> 3, sw1 = ((((256 + t) & 7) ^ (row1 & 7)) << 3);
    const u16* kbase = k  + ((size_t)bh << 18);
    const u16* vbase = vt + ((size_t)bh << 18);
    uint4 kr0, kr1, vr0, vr1;
    auto load_regs = [&](int kb){
        kr0 = *(const uint4*)(kbase + ((kb + row0) << 6) + sw0);
        kr1 = *(const uint4*)(kbase + ((kb + row1) << 6) + sw1);
        vr0 = *(const uint4*)(vbase + (row0 << 12) + kb + sw0);
        vr1 = *(const uint4*)(vbase + (row1 << 12) + kb + sw1);
    };
    auto write_lds = [&](){
        *(uint4*)(Kl + t * 8)         = kr0;
        *(uint4*)(Kl + (256 + t) * 8) = kr1;
        *(uint4*)(Vl + t * 8)         = vr0;
        *(uint4*)(Vl + (256 + t) * 8) = vr1;
    };

    // lane-local q row (q already pre-scaled by exp(temp)*log2e)
    const int qrow = qt * 64 + wave * 16 + l16;
    const u16* qb = q + (((size_t)bh * 4096 + qrow) << 6);
    bf16x8 qa[2];
    qa[0] = *(const bf16x8*)(qb + (lg << 3));
    qa[1] = *(const bf16x8*)(qb + 32 + (lg << 3));

    const uint4 ow = {0x3F803F80u, 0x3F803F80u, 0x3F803F80u, 0x3F803F80u};
    const bf16x8 ones = __builtin_bit_cast(bf16x8, ow);

    const f32x4 vzero = {0.f, 0.f, 0.f, 0.f};
    f32x4 o[4];                                  // o[dn][r] = O[q=l16][d=16dn+4lg+r]
    f32x4 o4 = vzero;                            // running denominator (all rows equal)
    #pragma unroll
    for (int i = 0; i < 4; ++i) o[i] = vzero;
    float mv = -INFINITY;                        // running max for row q=l16 (lane-local)

    // prologue: stage tile 0
    load_regs(0);
    write_lds();
    __syncthreads();

    for (int it = 0; it < 64; ++it){
        const int kb = it << 6;
        if (it < 63) load_regs(kb + 64);   // issue next-tile loads; latency hides under compute

        // S^T = K Q^T : lane holds S[q=l16][kv=16fc+4lg+r]  (log2 domain)
        f32x4 s[4];
        __builtin_amdgcn_s_setprio(1);
        #pragma unroll
        for (int fc = 0; fc < 4; ++fc){
            s[fc] = vzero;
            #pragma unroll
            for (int dc = 0; dc < 2; ++dc){
                bf16x8 kf = *(const bf16x8*)(Kl + (16 * fc + l16) * 64 +
                                             (((dc * 4 + lg) ^ (l16 & 7)) << 3));
                s[fc] = MFMA16(kf, qa[dc], s[fc]);
            }
        }
        __builtin_amdgcn_s_setprio(0);
        // diagonal mask: only in the tile containing this block's q range
        if (kb == qt * 64){
            int dd = wave * 16 + l16;            // kv offset of the diagonal for this lane
            #pragma unroll
            for (int fc = 0; fc < 4; ++fc)
                #pragma unroll
                for (int r = 0; r < 4; ++r)
                    if (dd == fc * 16 + 4 * lg + r) s[fc][r] = -1e30f;
        }
        // row max: max3 tree (8 ops) + 2 cross-lane steps
        float g0 = max3f(s[0][0], s[0][1], s[0][2]);
        float g1 = max3f(s[0][3], s[1][0], s[1][1]);
        float g2 = max3f(s[1][2], s[1][3], s[2][0]);
        float g3 = max3f(s[2][1], s[2][2], s[2][3]);
        float g4 = max3f(s[3][0], s[3][1], s[3][2]);
        float pm = fmaxf(max3f(max3f(g0, g1, g2), g3, g4), s[3][3]);
        pm = fmaxf(pm, __shfl_xor(pm, 16));
        pm = fmaxf(pm, __shfl_xor(pm, 32));
        // defer-max: rescale only when the running max grew materially
        if (__any(pm > mv + 8.0f)){
            float mn = fmaxf(mv, pm);
            float al = __builtin_amdgcn_exp2f(mv - mn);
            mv = mn;
            o4 *= al;
            #pragma unroll
            for (int dn = 0; dn < 4; ++dn)
                #pragma unroll
                for (int r = 0; r < 4; ++r) o[dn][r] *= al;
        }
        // P = exp2(S - m) -> bf16 pack via cvt_pk; denominator comes from ones-MFMA below
        #pragma unroll
        for (int fc = 0; fc < 4; ++fc){
            float p0 = __builtin_amdgcn_exp2f(s[fc][0] - mv);
            float p1 = __builtin_amdgcn_exp2f(s[fc][1] - mv);
            float p2 = __builtin_amdgcn_exp2f(s[fc][2] - mv);
            float p3 = __builtin_amdgcn_exp2f(s[fc][3] - mv);
            uint2 w;
            w.x = cvt_pk_bf16(p0, p1);
            w.y = cvt_pk_bf16(p2, p3);
            *(uint2*)&Pl[wave][l16 * 72 + 16 * fc + 4 * lg] = w;
        }
        // O^T += V^T P^T ; denominator row via ones-operand MFMA
        __builtin_amdgcn_s_setprio(1);
        #pragma unroll
        for (int kc = 0; kc < 2; ++kc){
            bf16x8 pa = *(const bf16x8*)(&Pl[wave][l16 * 72 + kc * 32 + lg * 8]);
            o4 = MFMA16(ones, pa, o4);
            #pragma unroll
            for (int dn = 0; dn < 4; ++dn){
                bf16x8 vf = *(const bf16x8*)(Vl + (16 * dn + l16) * 64 +
                                             (((kc * 4 + lg) ^ (l16 & 7)) << 3));
                o[dn] = MFMA16(vf, pa, o[dn]);
            }
        }
        __builtin_amdgcn_s_setprio(0);

        if (it < 63){
            __syncthreads();     // all waves done reading current tile
            write_lds();         // implicit vmcnt wait; only ds_writes between barriers
            __syncthreads();     // next tile ready
        }
    }
    // epilogue: lane owns row q=l16; d = 16*dn + 4*lg + r (r contiguous -> b64 stores)
    const int b = bh >> 3, h = bh & 7;
    const float inv = __builtin_amdgcn_rcpf(o4[0]);
    const int n = qt * 64 + wave * 16 + l16;
    size_t base = ((size_t)b * 4096 + n) * 512 + h * 64;
    #pragma unroll
    for (int dn = 0; dn < 4; ++dn){
        u16 e0 = f2bf(o[dn][0] * inv), e1 = f2bf(o[dn][1] * inv);
        u16 e2 = f2bf(o[dn][2] * inv), e3 = f2bf(o[dn][3] * inv);
        uint2 w;
        w.x = (u32)e0 | ((u32)e1 << 16);
        w.y = (u32)e2 | ((u32)e3 << 16);
        *(uint2*)&aout[base + dn * 16 + lg * 4] = w;
    }
}

// ---------------- GEMM2: out = aout @ w_out^T + bias; XCD-remapped (256 = 8*8*4) ----------------
__global__ __launch_bounds__(256) void gemm_out_kernel(const u16* __restrict__ A, const u16* __restrict__ Bt,
                                                       const float* __restrict__ bias,
                                                       float* __restrict__ out){
    __shared__ u16 ldsA[128 * 64];
    __shared__ u16 ldsB[128 * 64];
    const f32x4 vzero = {0.f, 0.f, 0.f, 0.f};
    f32x4 acc[4][4];
    #pragma unroll
    for (int m = 0; m < 4; ++m)
        #pragma unroll
        for (int n = 0; n < 4; ++n) acc[m][n] = vzero;

    const int bid = blockIdx.x;                 // [0,256)
    const int xcd = bid & 7, idx = bid >> 3;    // idx in [0,32)
    int brow = (xcd * 8 + (idx & 7)) * 128;     // brow-block in [0,64)
    int bcol = (idx >> 3) * 128;                // bcol-block in [0,4)
    gemm_core(A, Bt, brow, bcol, ldsA, ldsB, acc);

    const int t = threadIdx.x, lane = t & 63, wave = t >> 6;
    const int l16 = lane & 15, lg = lane >> 4;
    const int wrow = (wave & 1) << 6, wcol = (wave >> 1) << 6;
    #pragma unroll
    for (int n = 0; n < 4; ++n){
        int e = bcol + wcol + 16 * n + l16;
        float bv = bias[e];
        #pragma unroll
        for (int m = 0; m < 4; ++m)
            #pragma unroll
            for (int r = 0; r < 4; ++r){
                int mg = brow + wrow + 16 * m + 4 * lg + r;
                out[(size_t)mg * 512 + e] = acc[m][n][r] + bv;
            }
    }
}

extern "C" void kernel_launch(void* const* d_in, const int* in_sizes, int n_in,
                              void* d_out, int out_size, void* d_ws, size_t ws_size,
                              hipStream_t stream){
    (void)in_sizes; (void)n_in; (void)out_size; (void)ws_size;
    const float* x     = (const float*)d_in[0];
    const float* w_qkv = (const float*)d_in[1];
    const float* w_out = (const float*)d_in[2];
    const float* b_out = (const float*)d_in[3];
    const float* temp  = (const float*)d_in[4];
    float* out = (float*)d_out;

    u16* ws   = (u16*)d_ws;
    u16* xbf  = ws;                              // 8192*512
    u16* wqt  = xbf + 8192 * 512;                // 1536*512
    u16* wot  = wqt + 1536 * 512;                // 512*512
    u16* qws  = wot + 512 * 512;                 // 16*4096*64
    u16* kws  = qws + 16 * 4096 * 64;
    u16* vtws = kws + 16 * 4096 * 64;
    u16* aout = xbf;                             // alias: xbf dead after GEMM1

    cvt_all_kernel<<<3072, 256, 0, stream>>>(x, w_qkv, w_out, xbf, wqt, wot);
    gemm_qkv_kernel<<<768, 256, 0, stream>>>(xbf, wqt, qws, kws, vtws, temp);
    attn_kernel<<<1024, 256, 0, stream>>>(qws, kws, vtws, aout);
    gemm_out_kernel<<<256, 256, 0, stream>>>(aout, wot, b_out, out);
}